// Round 8
// baseline (318488.110 us; speedup 1.0000x reference)
//
#include <hip/hip_runtime.h>
#include <stdint.h>

#define TSEQ 32768
#define HDIM 512
#define NWGL 32          // workgroups per layer
#define WGT  512         // threads per workgroup (8 waves)
#define POISON32 0x7FA57FA5u   // both u16 halves are bf16 NaN; finite h never matches
#define FAST_TRIES 64

typedef float f4 __attribute__((ext_vector_type(4)));

__device__ __forceinline__ float sigf(float x){ return 1.f/(1.f+__expf(-x)); }
__device__ __forceinline__ float tanhf_fast(float x){ return 1.f - 2.f/(1.f+__expf(2.f*x)); }

// guaranteed-visibility path (MALL)
__device__ __forceinline__ uint64_t agload64(const uint64_t* p){
  return __hip_atomic_load(p, __ATOMIC_RELAXED, __HIP_MEMORY_SCOPE_AGENT);
}
__device__ __forceinline__ void agstore32(uint32_t* p, uint32_t v){
  __hip_atomic_store(p, v, __ATOMIC_RELAXED, __HIP_MEMORY_SCOPE_AGENT);
}
// fast path: plain store updates the (shared, same-XCD) L2; sc0 load bypasses L1.
__device__ __forceinline__ void wgstore32(uint32_t* p, uint32_t v){
  __hip_atomic_store(p, v, __ATOMIC_RELAXED, __HIP_MEMORY_SCOPE_WORKGROUP);
}
// non-blocking issue: compiler inserts the waitcnt before first USE of result
__device__ __forceinline__ uint64_t l2load64_nb(const uint64_t* p){
  uint64_t v; uint64_t a = (uint64_t)p;
  asm volatile("global_load_dwordx2 %0, %1, off sc0" : "=v"(v) : "v"(a));
  return v;
}
// blocking re-load for the spin
__device__ __forceinline__ uint64_t l2load64(const uint64_t* p){
  uint64_t v; uint64_t a = (uint64_t)p;
  asm volatile("global_load_dwordx2 %0, %1, off sc0\n\ts_waitcnt vmcnt(0)"
               : "=v"(v) : "v"(a) : "memory");
  return v;
}

__device__ __forceinline__ uint32_t f2bf(float f){   // RNE f32->bf16 (finite inputs)
  uint32_t u = __float_as_uint(f);
  u += 0x7fffu + ((u>>16)&1u);
  return u>>16;
}
__device__ __forceinline__ float bf_lo(uint32_t u){ return __uint_as_float(u<<16); }
__device__ __forceinline__ float bf_hi(uint32_t u){ return __uint_as_float(u & 0xffff0000u); }
__device__ __forceinline__ bool pois2(uint64_t v){
  return (((uint32_t)v)==POISON32) | (((uint32_t)(v>>32))==POISON32);
}
// r5's 16B-granule XOR swizzle over 128 granules (measured conflict-free)
__device__ __forceinline__ int swz(int g){ return (g & ~15) | ((g & 15) ^ (g >> 4)); }

// unpack u64 (4 bf16) -> f4 into swizzled LDS logical granule j
__device__ __forceinline__ void unpack_store(uint64_t v, float* buf, int j){
  uint32_t aa = (uint32_t)v, bb = (uint32_t)(v>>32);
  f4 f; f.x = bf_lo(aa); f.y = bf_hi(aa); f.z = bf_lo(bb); f.w = bf_hi(bb);
  *(f4*)&buf[swz(j)*4] = f;
}
__device__ __forceinline__ f4 ntload(const float* p){
  return __builtin_nontemporal_load((const f4*)p);
}

#define PIN4(v) asm volatile("" : "+v"((v).x), "+v"((v).y), "+v"((v).z), "+v"((v).w))

// hh matvec over 64-wide K chunk (kc in 0..7) from swizzled LDS (r5 pattern, 0 conflicts)
#define MV(bufptr, W) do { \
  const float* _b = (bufptr); \
  _Pragma("unroll") \
  for (int q=0;q<16;q++){ \
    f4 hv = *(const f4*)&_b[(((kc<<4)|(q^kc))<<2)]; \
    s0 = fmaf(W[q].x, hv.x, s0); s1 = fmaf(W[q].y, hv.y, s1); \
    s2 = fmaf(W[q].z, hv.z, s2); s3 = fmaf(W[q].w, hv.w, s3); } \
} while(0)

// ---- poison comm arrays + zero claim table (agent-scope stores) ----
__global__ __launch_bounds__(256,1)
void poison_kernel(uint64_t* __restrict__ a, int n64, int* __restrict__ claim){
  const uint64_t P = (((uint64_t)POISON32)<<32) | (uint64_t)POISON32;
  int i = blockIdx.x*256 + threadIdx.x;
  const int st = gridDim.x*256;
  for (; i < n64; i += st)
    __hip_atomic_store(a+i, P, __ATOMIC_RELAXED, __HIP_MEMORY_SCOPE_AGENT);
  if (blockIdx.x == 0 && threadIdx.x < 32)
    __hip_atomic_store(claim + threadIdx.x, 0, __ATOMIC_RELAXED, __HIP_MEMORY_SCOPE_AGENT);
}

// ---- persistent 2-layer LSTM scan, claim-verified XCD co-location ----
// 2048 blocks x 512 thr. Each block reads its physical XCD (HW_REG_XCC_ID) and
// claims a slot: first 32 blocks of the first XCD to appear -> layer0, first 32
// of the second XCD -> layer1, all others exit. Producers and consumers of the
// recurrent line share one L2 by construction.
// Per wg 64 gate rows = 16 dims x 4 gates. Thread: row = tid>>3, kc = tid&7.
// W_hh slice (64 f32) in registers; W_ih slice in LDS as bf16.
__global__ __launch_bounds__(WGT, 2)
void lstm_persistent(const float* __restrict__ x,
                     const float* __restrict__ wih0, const float* __restrict__ whh0,
                     const float* __restrict__ bih0, const float* __restrict__ bhh0,
                     const float* __restrict__ wih1, const float* __restrict__ whh1,
                     const float* __restrict__ bih1, const float* __restrict__ bhh1,
                     uint32_t* __restrict__ hsF0, uint32_t* __restrict__ hsF1,
                     uint32_t* __restrict__ hsM0, uint32_t* __restrict__ hsM1,
                     int* __restrict__ claim)
{
  // ---- claim-based placement: layer/wgl from physical XCD ----
  __shared__ int encS;
  if (threadIdx.x == 0){
    int xcc;
    asm volatile("s_getreg_b32 %0, hwreg(HW_REG_XCC_ID)" : "=s"(xcc));
    xcc &= 7;
    int enc = -1;
    int slot = atomicAdd(&claim[xcc], 1);
    if (slot < NWGL){
      int role;
      if (slot == 0){
        role = atomicAdd(&claim[8], 1);
        __hip_atomic_store(&claim[9+xcc], role+1, __ATOMIC_RELAXED, __HIP_MEMORY_SCOPE_AGENT);
      } else {
        do {
          role = __hip_atomic_load(&claim[9+xcc], __ATOMIC_RELAXED, __HIP_MEMORY_SCOPE_AGENT);
        } while (role == 0);
        role -= 1;
      }
      if (role < 2) enc = role*NWGL + slot;   // role 0 -> layer0, role 1 -> layer1
    }
    encS = enc;
  }
  __syncthreads();
  const int enc = encS;
  if (enc < 0) return;
  const int layer = enc >> 5;
  const int wgl   = enc & 31;

  const int tid   = threadIdx.x;
  const int kc    = tid & 7;
  const int row   = tid >> 3;       // 0..63
  const int dl    = row >> 2;
  const int g     = row & 3;
  const int grow  = g*HDIM + wgl*16 + dl;
  const int lane  = tid & 63;
  const int wv    = tid >> 6;       // wave 0..7 (dims 2wv, 2wv+1)

  const float* Wih = layer ? wih1 : wih0;
  const float* Whh = layer ? whh1 : whh0;
  uint32_t* dstF = layer ? hsF1 : hsF0;
  uint32_t* dstM = layer ? hsM1 : hsM0;
  const float bias = (layer?bih1:bih0)[grow] + (layer?bhh1:bhh0)[grow];

  // W_hh: 64 f32/thread, register-resident (r4-proven class)
  f4 wr[16];
  {
    const float* wrp = Whh + (size_t)grow*HDIM + kc*64;
    #pragma unroll
    for (int q=0;q<16;q++) wr[q] = *(const f4*)(wrp+4*q);
  }
  #pragma unroll
  for (int q=0;q<16;q++) PIN4(wr[q]);

  __shared__ uint32_t wiL[64*256];  // W_ih bf16x2, 64 KB, conflict-free layout
  __shared__ float xa[2][HDIM];     // step input, double buffered, swizzled f32
  __shared__ float hr[2][HDIM];     // recurrent h, double buffered, swizzled f32

  // stage W_ih -> LDS bf16. granule idx = row*64 + qq*8 + kc:
  // consecutive 8 lanes vary kc -> granule%8 = kc -> distinct bank-quads (R+W).
  {
    const float* wip = Wih + (size_t)grow*HDIM + kc*64;
    #pragma unroll
    for (int qq=0; qq<8; qq++){
      f4 a = *(const f4*)(wip + 8*qq);
      f4 c = *(const f4*)(wip + 8*qq + 4);
      uint4 u;
      u.x = f2bf(a.x) | (f2bf(a.y)<<16);
      u.y = f2bf(a.z) | (f2bf(a.w)<<16);
      u.z = f2bf(c.x) | (f2bf(c.y)<<16);
      u.w = f2bf(c.z) | (f2bf(c.w)<<16);
      *(uint4*)&wiL[(row*64 + qq*8 + kc)*4] = u;
    }
  }

  float cst = 0.f;
  f4 xpref = (f4){0.f,0.f,0.f,0.f};

  // ---- pre-loop staging ----
  if (tid < 128){
    *(f4*)&hr[0][swz(tid)*4] = (f4){0.f,0.f,0.f,0.f};
  } else if (tid < 256){
    const int j = tid - 128;
    if (!layer){
      *(f4*)&xa[0][swz(j)*4] = ntload(x + j*4);
      xpref = ntload(x + HDIM + j*4);
    } else {
      const uint64_t* p = (const uint64_t*)hsM0 + j;
      uint64_t v = agload64(p);
      while (pois2(v)) v = agload64(p);
      unpack_store(v, &xa[0][0], j);
    }
  }
  __syncthreads();

  #pragma unroll 1
  for (int t = 0; t < TSEQ; ++t){
    float s0=0.f, s1=0.f, s2=0.f, s3=0.f;

    // (a) issue polls early, non-blocking — latency overlaps the ih matvec
    const uint64_t *pf = nullptr, *pm = nullptr, *pxm = nullptr;
    uint64_t pv = 0, xv = 0;
    if (tid < 128){
      if (t > 0){
        pf = (const uint64_t*)(dstF + (size_t)(t-1)*256) + tid;
        pm = (const uint64_t*)(dstM + (size_t)(t-1)*256) + tid;
        pv = l2load64_nb(pf);
      }
    } else if (tid < 256 && layer){
      if (t+1 < TSEQ){
        pxm = (const uint64_t*)(hsM0 + (size_t)(t+1)*256) + (tid-128);
        xv = agload64(pxm);
      }
    }

    // (b) ih matvec: bf16 weights from LDS x staged input (off recurrent chain)
    {
      const float* xb = &xa[t&1][0];
      const uint32_t* wbase = &wiL[(row*64 + kc)*4];
      #pragma unroll
      for (int qq=0; qq<8; qq++){
        uint4 u = *(const uint4*)&wbase[qq*32];   // granule row*64+qq*8+kc
        f4 a0 = *(const f4*)&xb[(((kc<<4)|((2*qq)^kc))<<2)];
        f4 a1 = *(const f4*)&xb[(((kc<<4)|((2*qq+1)^kc))<<2)];
        s0 = fmaf(bf_lo(u.x), a0.x, s0); s1 = fmaf(bf_hi(u.x), a0.y, s1);
        s2 = fmaf(bf_lo(u.y), a0.z, s2); s3 = fmaf(bf_hi(u.y), a0.w, s3);
        s0 = fmaf(bf_lo(u.z), a1.x, s0); s1 = fmaf(bf_hi(u.z), a1.y, s1);
        s2 = fmaf(bf_lo(u.w), a1.z, s2); s3 = fmaf(bf_hi(u.w), a1.w, s3);
      }
    }

    // (c) finish polls / stage next input
    if (tid < 128){
      if (t > 0){
        uint64_t v = pv; int k = 0;
        while (pois2(v)){
          ++k;
          v = (k >= FAST_TRIES && (k & 1)) ? agload64(pm) : l2load64(pf);
        }
        unpack_store(v, &hr[t&1][0], tid);
      }
    } else if (tid < 256){
      const int j = tid - 128;
      if (!layer){
        if (t+1 < TSEQ){
          *(f4*)&xa[(t+1)&1][swz(j)*4] = xpref;
          const int tn = (t+2 < TSEQ) ? t+2 : t;
          xpref = ntload(x + (size_t)tn*HDIM + j*4);
        }
      } else {
        if (t+1 < TSEQ){
          uint64_t v = xv;
          while (pois2(v)) v = agload64(pxm);   // layer0 runs ahead: lag-absorbed
          unpack_store(v, &xa[(t+1)&1][0], j);
        }
      }
    }
    __syncthreads();   // single barrier per step

    // (d) hh matvec (registers x LDS, conflict-free) + in-wave reduce + gates
    MV(&hr[t&1][0], wr);
    float s = (s0+s1)+(s2+s3);
    s += __shfl_xor(s,1); s += __shfl_xor(s,2); s += __shfl_xor(s,4);
    s += bias;
    float fv = __shfl_down(s,8), gv = __shfl_down(s,16), ov = __shfl_down(s,24);
    float gi = sigf(s), gf = sigf(fv), gg = tanhf_fast(gv), go = sigf(ov);
    cst = fmaf(gf, cst, gi*gg);
    float h = go * tanhf_fast(cst);           // valid on lanes 0 and 32
    float ho = __shfl(h, 32);
    if (lane == 0){
      uint32_t pk = f2bf(h) | (f2bf(ho)<<16); // dims 2wv, 2wv+1
      wgstore32(dstF + (size_t)t*256 + wgl*8 + wv, pk);
      agstore32(dstM + (size_t)t*256 + wgl*8 + wv, pk);
    }
  }
}

// ---- head ----
__global__ __launch_bounds__(256)
void transpose_kernel(const float* __restrict__ w1, const float* __restrict__ w2,
                      float* __restrict__ w1t, float* __restrict__ w2t){
  int i = blockIdx.x*256 + threadIdx.x;
  if (i < 128*512){ int rr = i >> 9, k = i & 511; w1t[k*128 + rr] = w1[i]; }
  if (i < 64*128){ int rr = i >> 7, k = i & 127; w2t[k*64 + rr] = w2[i]; }
}

__global__ __launch_bounds__(128)
void mlp1_kernel(const uint32_t* __restrict__ hs1u, const float* __restrict__ w1t,
                 const float* __restrict__ b1, float* __restrict__ z1){
  __shared__ float hsl[2048];             // 4 rows x 512
  const int tid = threadIdx.x;
  const size_t row0 = (size_t)blockIdx.x*4;
  const uint4* src = (const uint4*)(hs1u + row0*256);
  #pragma unroll
  for (int q=0;q<2;q++){
    int jj = tid + q*128;                 // uint4 index 0..255
    uint4 u = src[jj];
    int base = jj*8;
    hsl[base+0] = bf_lo(u.x); hsl[base+1] = bf_hi(u.x);
    hsl[base+2] = bf_lo(u.y); hsl[base+3] = bf_hi(u.y);
    hsl[base+4] = bf_lo(u.z); hsl[base+5] = bf_hi(u.z);
    hsl[base+6] = bf_lo(u.w); hsl[base+7] = bf_hi(u.w);
  }
  __syncthreads();
  float a0=0.f,a1=0.f,a2=0.f,a3=0.f;
  #pragma unroll 4
  for (int k=0;k<512;k++){
    float wv = w1t[k*128 + tid];
    a0 = fmaf(wv, hsl[k],      a0);
    a1 = fmaf(wv, hsl[512+k],  a1);
    a2 = fmaf(wv, hsl[1024+k], a2);
    a3 = fmaf(wv, hsl[1536+k], a3);
  }
  float bb = b1[tid];
  z1[(row0+0)*128 + tid] = fmaxf(a0+bb, 0.f);
  z1[(row0+1)*128 + tid] = fmaxf(a1+bb, 0.f);
  z1[(row0+2)*128 + tid] = fmaxf(a2+bb, 0.f);
  z1[(row0+3)*128 + tid] = fmaxf(a3+bb, 0.f);
}

template<int NF_>
__global__ void stats_partial(const float* __restrict__ z, float* __restrict__ part){
  const int cf = threadIdx.x;
  const int bb = blockIdx.x;             // 64 blocks x 512 rows
  float s=0.f, sq=0.f;
  const float* p = z + (size_t)bb*512*NF_ + cf;
  for (int rr=0; rr<512; rr++){
    float v = p[(size_t)rr*NF_];
    s += v; sq = fmaf(v, v, sq);
  }
  part[(bb*NF_ + cf)*2+0] = s;
  part[(bb*NF_ + cf)*2+1] = sq;
}

template<int NF_>
__global__ void stats_final(const float* __restrict__ part, const float* __restrict__ gamma,
                            const float* __restrict__ beta, float* __restrict__ sc,
                            float* __restrict__ sh){
  const int cf = threadIdx.x;
  float s=0.f, sq=0.f;
  for (int bb=0;bb<64;bb++){ s += part[(bb*NF_+cf)*2]; sq += part[(bb*NF_+cf)*2+1]; }
  const float inv = 1.f/32768.f;
  float m = s*inv;
  float v = fmaf(sq, inv, -m*m);
  float scale = gamma[cf]*rsqrtf(v + 1e-5f);
  sc[cf] = scale;
  sh[cf] = fmaf(-m, scale, beta[cf]);
}

__global__ __launch_bounds__(64)
void mlp2_kernel(const float* __restrict__ z1, const float* __restrict__ w2t,
                 const float* __restrict__ b2, const float* __restrict__ sc1,
                 const float* __restrict__ sh1, float* __restrict__ z2){
  __shared__ float zl[1024];              // 8 rows x 128 (BN-applied)
  const int tid = threadIdx.x;
  const size_t row0 = (size_t)blockIdx.x*8;
  #pragma unroll
  for (int q=0;q<4;q++){
    int idx = tid + q*64;                 // float4 index 0..255
    float4 v = *(const float4*)&z1[row0*128 + idx*4];
    int k0 = (idx*4) & 127;
    v.x = fmaf(v.x, sc1[k0+0], sh1[k0+0]);
    v.y = fmaf(v.y, sc1[k0+1], sh1[k0+1]);
    v.z = fmaf(v.z, sc1[k0+2], sh1[k0+2]);
    v.w = fmaf(v.w, sc1[k0+3], sh1[k0+3]);
    *(float4*)&zl[idx*4] = v;
  }
  __syncthreads();
  float acc[8] = {0.f,0.f,0.f,0.f,0.f,0.f,0.f,0.f};
  #pragma unroll 4
  for (int k=0;k<128;k++){
    float wv = w2t[k*64 + tid];
    #pragma unroll
    for (int rr=0;rr<8;rr++) acc[rr] = fmaf(wv, zl[rr*128 + k], acc[rr]);
  }
  float bb = b2[tid];
  #pragma unroll
  for (int rr=0;rr<8;rr++)
    z2[(row0+rr)*64 + tid] = fmaxf(acc[rr]+bb, 0.f);
}

__global__ __launch_bounds__(256)
void mlp3_kernel(const float* __restrict__ z2, const float* __restrict__ w3,
                 const float* __restrict__ b3, const float* __restrict__ sc2,
                 const float* __restrict__ sh2, float* __restrict__ out){
  const int tid = threadIdx.x;
  const int lane = tid & 63;
  const size_t row = (size_t)blockIdx.x*4 + (tid>>6);   // one wave per row
  float v = fmaf(z2[row*64 + lane], sc2[lane], sh2[lane]);
  float p0 = v*w3[lane], p1 = v*w3[64+lane], p2 = v*w3[128+lane];
  #pragma unroll
  for (int off=32; off; off>>=1){
    p0 += __shfl_xor(p0, off);
    p1 += __shfl_xor(p1, off);
    p2 += __shfl_xor(p2, off);
  }
  if (lane == 0){
    out[row*3+0] = p0 + b3[0];
    out[row*3+1] = p1 + b3[1];
    out[row*3+2] = p2 + b3[2];
  }
}

extern "C" void kernel_launch(void* const* d_in, const int* in_sizes, int n_in,
                              void* d_out, int out_size, void* d_ws, size_t ws_size,
                              hipStream_t stream){
  (void)in_sizes; (void)n_in; (void)out_size;
  const float* x    = (const float*)d_in[0];
  const float* wih0 = (const float*)d_in[1];
  const float* whh0 = (const float*)d_in[2];
  const float* bih0 = (const float*)d_in[3];
  const float* bhh0 = (const float*)d_in[4];
  const float* wih1 = (const float*)d_in[5];
  const float* whh1 = (const float*)d_in[6];
  const float* bih1 = (const float*)d_in[7];
  const float* bhh1 = (const float*)d_in[8];
  const float* w1   = (const float*)d_in[9];
  const float* b1   = (const float*)d_in[10];
  const float* g1   = (const float*)d_in[11];
  const float* be1  = (const float*)d_in[12];
  const float* w2   = (const float*)d_in[13];
  const float* b2   = (const float*)d_in[14];
  const float* g2   = (const float*)d_in[15];
  const float* be2  = (const float*)d_in[16];
  const float* w3   = (const float*)d_in[17];
  const float* b3   = (const float*)d_in[18];
  float* out = (float*)d_out;

  if (ws_size < (size_t)(128u<<20) + 4096u) return;

  uint8_t* wb = (uint8_t*)d_ws;
  uint32_t* hsF0 = (uint32_t*)wb;                        // [0,32MB)  fast, layer0
  uint32_t* hsF1 = (uint32_t*)(wb + (size_t)(32u<<20));  // [32,64MB) fast, layer1
  uint32_t* hsM0 = (uint32_t*)(wb + (size_t)(64u<<20));  // [64,96MB) mirror, layer0
  uint32_t* hsM1 = (uint32_t*)(wb + (size_t)(96u<<20));  // [96,128MB) mirror, layer1
  int* claim     = (int*)(wb + (size_t)(128u<<20));      // 32 ints, zeroed per launch
  // head scratch aliases hsM0 region; written only AFTER the scan completes
  float* z1    = (float*)(wb + (size_t)(64u<<20));       // [64,80MB)
  float* z2    = (float*)(wb + (size_t)(80u<<20));       // [80,88MB)
  float* w1t   = (float*)(wb + (size_t)(88u<<20));       // 256 KB
  float* w2t   = w1t + 65536;                            // 32 KB
  float* part1 = w2t + 8192;
  float* part2 = part1 + 16384;
  float* sc1   = part2 + 8192;
  float* sh1   = sc1 + 128;
  float* sc2   = sh1 + 128;
  float* sh2   = sc2 + 64;

  poison_kernel<<<1024, 256, 0, stream>>>((uint64_t*)wb, 16777216, claim);
  lstm_persistent<<<2048, WGT, 0, stream>>>(x, wih0, whh0, bih0, bhh0,
                                            wih1, whh1, bih1, bhh1,
                                            hsF0, hsF1, hsM0, hsM1, claim);
  transpose_kernel<<<256, 256, 0, stream>>>(w1, w2, w1t, w2t);
  mlp1_kernel<<<8192, 128, 0, stream>>>(hsF1, w1t, b1, z1);
  stats_partial<128><<<64, 128, 0, stream>>>(z1, part1);
  stats_final<128><<<1, 128, 0, stream>>>(part1, g1, be1, sc1, sh1);
  mlp2_kernel<<<4096, 64, 0, stream>>>(z1, w2t, b2, sc1, sh1, z2);
  stats_partial<64><<<64, 64, 0, stream>>>(z2, part2);
  stats_final<64><<<1, 64, 0, stream>>>(part2, g2, be2, sc2, sh2);
  mlp3_kernel<<<8192, 256, 0, stream>>>(z2, w3, b3, sc2, sh2, out);
}

// Round 9
// 108624.487 us; speedup vs baseline: 2.9320x; 2.9320x over previous
//
#include <hip/hip_runtime.h>
#include <stdint.h>

#define TSEQ 32768
#define HDIM 512
#define NWGL 32         // workgroups per layer (64 total)
#define WGT  512        // threads per workgroup (8 waves)
#define POISON32 0x7FA57FA5u   // NaN pattern; finite values never equal it

typedef float f4 __attribute__((ext_vector_type(4)));

__device__ __forceinline__ float sigf(float x){ return 1.f/(1.f+__expf(-x)); }
__device__ __forceinline__ float tanhf_fast(float x){ return 1.f - 2.f/(1.f+__expf(2.f*x)); }

__device__ __forceinline__ uint64_t agload64(const uint64_t* p){
  return __hip_atomic_load(p, __ATOMIC_RELAXED, __HIP_MEMORY_SCOPE_AGENT);
}
__device__ __forceinline__ void agstore32(uint32_t* p, uint32_t v){
  __hip_atomic_store(p, v, __ATOMIC_RELAXED, __HIP_MEMORY_SCOPE_AGENT);
}
__device__ __forceinline__ uint32_t f2bf(float f){   // RNE f32->bf16 (finite inputs)
  uint32_t u = __float_as_uint(f);
  u += 0x7fffu + ((u>>16)&1u);
  return u>>16;
}
__device__ __forceinline__ float bf_lo(uint32_t u){ return __uint_as_float(u<<16); }
__device__ __forceinline__ float bf_hi(uint32_t u){ return __uint_as_float(u & 0xffff0000u); }
__device__ __forceinline__ bool pois2(uint64_t v){
  return (((uint32_t)v)==POISON32) | (((uint32_t)(v>>32))==POISON32);
}
__device__ __forceinline__ f4 asf4(uint64_t a, uint64_t b){
  f4 f; f.x=__uint_as_float((uint32_t)a); f.y=__uint_as_float((uint32_t)(a>>32));
        f.z=__uint_as_float((uint32_t)b); f.w=__uint_as_float((uint32_t)(b>>32));
  return f;
}
__device__ __forceinline__ f4 ntload(const float* p){
  return __builtin_nontemporal_load((const f4*)p);
}
// 16B-granule XOR swizzle: granule g -> (g & ~15) | ((g&15) ^ (g>>4))  [r5-proven]
__device__ __forceinline__ int swz(int g){ return (g & ~15) | ((g & 15) ^ (g >> 4)); }

#define PIN4(v) asm volatile("" : "+v"((v).x), "+v"((v).y), "+v"((v).z), "+v"((v).w))

// hh matvec over this thread's 64-wide K chunk (kc in 0..7) from swizzled LDS.
// All 8 rows of a wave share kc-granules -> broadcast, 0 conflicts (r5-measured).
#define MV(bufptr, W) do { \
  const float* _b = (bufptr); \
  _Pragma("unroll") \
  for (int q=0;q<16;q++){ \
    f4 hv = *(const f4*)&_b[(((kc<<4)|(q^kc))<<2)]; \
    s0 = fmaf(W[q].x, hv.x, s0); s1 = fmaf(W[q].y, hv.y, s1); \
    s2 = fmaf(W[q].z, hv.z, s2); s3 = fmaf(W[q].w, hv.w, s3); } \
} while(0)

// ---- poison comm arrays (agent-scope stores) ----
__global__ __launch_bounds__(256,1)
void poison_kernel(uint64_t* __restrict__ a, int n64){
  const uint64_t P = (((uint64_t)POISON32)<<32) | (uint64_t)POISON32;
  int i = blockIdx.x*256 + threadIdx.x;
  const int st = gridDim.x*256;
  for (; i < n64; i += st)
    __hip_atomic_store(a+i, P, __ATOMIC_RELAXED, __HIP_MEMORY_SCOPE_AGENT);
}

// ---- persistent 2-layer LSTM scan, all-MALL comm (r1-proven path) ----
// 64 wgs x 512 thr. wg<32 -> layer0 (input x), wg>=32 -> layer1 (input hs0).
// Per wg: 64 gate rows = 16 dims x 4 gates; row = tid>>3, kc = tid&7.
// W_hh slice (64 f32) register-resident (r7/r8-proven class at VGPR=120);
// W_ih slice bf16x2 in LDS, u32 layout -> 2 lanes/bank = conflict-free (m136).
__global__ __launch_bounds__(WGT, 2)
void lstm_persistent(const float* __restrict__ x,
                     const float* __restrict__ wih0, const float* __restrict__ whh0,
                     const float* __restrict__ bih0, const float* __restrict__ bhh0,
                     const float* __restrict__ wih1, const float* __restrict__ whh1,
                     const float* __restrict__ bih1, const float* __restrict__ bhh1,
                     float* __restrict__ hs0, float* __restrict__ hs1)
{
  const int wg    = blockIdx.x;
  const int layer = (wg >= NWGL) ? 1 : 0;
  const int wgl   = layer ? wg - NWGL : wg;
  const int tid   = threadIdx.x;
  const int kc    = tid & 7;        // K-chunk [kc*64, kc*64+64)
  const int row   = tid >> 3;       // 0..63 local gate row
  const int dl    = row >> 2;       // 0..15 local dim
  const int g     = row & 3;        // gate: 0=i 1=f 2=g 3=o
  const int grow  = g*HDIM + wgl*16 + dl;
  const int lane  = tid & 63;
  const int wv    = tid >> 6;

  const float* Wih = layer ? wih1 : wih0;
  const float* Whh = layer ? whh1 : whh0;
  float* dst = layer ? hs1 : hs0;
  const float bias = (layer?bih1:bih0)[grow] + (layer?bhh1:bhh0)[grow];

  // W_hh: 64 f32/thread in registers
  f4 wr[16];
  {
    const float* wrp = Whh + (size_t)grow*HDIM + kc*64;
    #pragma unroll
    for (int q=0;q<16;q++) wr[q] = *(const f4*)(wrp+4*q);
  }
  #pragma unroll
  for (int q=0;q<16;q++) PIN4(wr[q]);   // one-time pin

  __shared__ uint32_t wiL[32*512];  // W_ih bf16x2: [p][row*8+kc], 64 KB
  __shared__ float xa[2][HDIM];     // step input, double buffered, swizzled
  __shared__ float hr[2][HDIM];     // recurrent h, double buffered, swizzled

  // stage W_ih -> LDS (pair p of thread (row,kc) at wiL[p*512 + row*8 + kc]).
  // For fixed p: 64 lanes hit 64 consecutive words -> 2 lanes/bank, free.
  {
    const float* wip = Wih + (size_t)grow*HDIM + kc*64;
    uint32_t* wp = &wiL[row*8 + kc];
    #pragma unroll
    for (int p=0;p<32;p++)
      wp[p*512] = f2bf(wip[2*p]) | (f2bf(wip[2*p+1])<<16);
  }

  float cst = 0.f;                // cell state (publisher lanes)
  f4 xpref = (f4){0.f,0.f,0.f,0.f};

  // ---- pre-loop staging ----
  if (tid < 128){
    *(f4*)&hr[0][swz(tid)*4] = (f4){0.f,0.f,0.f,0.f};
  } else if (tid < 256){
    const int j = tid - 128;
    if (!layer){
      *(f4*)&xa[0][swz(j)*4] = ntload(x + j*4);
      xpref = ntload(x + HDIM + j*4);
    } else {
      const uint64_t* p = (const uint64_t*)hs0 + j*2;
      uint64_t a = agload64(p), b = agload64(p+1);
      while (pois2(a)) a = agload64(p);
      while (pois2(b)) b = agload64(p+1);
      *(f4*)&xa[0][swz(j)*4] = asf4(a,b);
    }
  }
  __syncthreads();

  #pragma unroll 1
  for (int t = 0; t < TSEQ; ++t){
    // (a) issue polls early: latency overlaps the ih matvec
    const uint64_t *ph = nullptr, *px = nullptr;
    uint64_t h0=0, h1=0, x0=0, x1=0;
    if (tid < 128){
      if (t > 0){
        ph = (const uint64_t*)(dst + (size_t)(t-1)*HDIM) + tid*2;
        h0 = agload64(ph); h1 = agload64(ph+1);
      }
    } else if (tid < 256 && layer){
      if (t+1 < TSEQ){
        px = (const uint64_t*)(hs0 + (size_t)(t+1)*HDIM) + (tid-128)*2;
        x0 = agload64(px); x1 = agload64(px+1);
      }
    }

    // (b) ih matvec: bf16 W_ih from LDS (u32, conflict-free) x staged input
    float s0=0.f, s1=0.f, s2=0.f, s3=0.f;
    {
      const float* xb = &xa[t&1][0];
      const uint32_t* wp = &wiL[row*8 + kc];
      #pragma unroll
      for (int q=0;q<16;q++){
        f4 a = *(const f4*)&xb[(((kc<<4)|(q^kc))<<2)];   // logical elems kc*64+4q..
        uint32_t u0 = wp[(2*q)*512];
        uint32_t u1 = wp[(2*q+1)*512];
        s0 = fmaf(bf_lo(u0), a.x, s0); s1 = fmaf(bf_hi(u0), a.y, s1);
        s2 = fmaf(bf_lo(u1), a.z, s2); s3 = fmaf(bf_hi(u1), a.w, s3);
      }
    }

    // (c) finish polls / stage next input
    if (tid < 128){
      if (t > 0){
        while (pois2(h0)) h0 = agload64(ph);
        while (pois2(h1)) h1 = agload64(ph+1);
        *(f4*)&hr[t&1][swz(tid)*4] = asf4(h0,h1);
      }
    } else if (tid < 256){
      const int j = tid - 128;
      if (!layer){
        if (t+1 < TSEQ){
          *(f4*)&xa[(t+1)&1][swz(j)*4] = xpref;
          const int tn = (t+2 < TSEQ) ? t+2 : t;
          xpref = ntload(x + (size_t)tn*HDIM + j*4);
        }
      } else {
        if (t+1 < TSEQ){
          while (pois2(x0)) x0 = agload64(px);
          while (pois2(x1)) x1 = agload64(px+1);
          *(f4*)&xa[(t+1)&1][swz(j)*4] = asf4(x0,x1);
        }
      }
    }
    __syncthreads();   // single barrier per step

    // (d) hh matvec + in-wave reduce + gates + publish
    MV(&hr[t&1][0], wr);
    float s = (s0+s1)+(s2+s3);
    s += __shfl_xor(s,1); s += __shfl_xor(s,2); s += __shfl_xor(s,4);
    s += bias;
    float fv = __shfl_down(s,8), gv = __shfl_down(s,16), ov = __shfl_down(s,24);
    if ((lane & 31) == 0){
      float gi = sigf(s), gf = sigf(fv), gg = tanhf_fast(gv), go = sigf(ov);
      cst = fmaf(gf, cst, gi*gg);
      float h = go * tanhf_fast(cst);
      agstore32((uint32_t*)(dst + (size_t)t*HDIM + wgl*16 + 2*wv + (lane>>5)),
                __float_as_uint(h));
    }
  }
}

// ---- head ----
__global__ __launch_bounds__(256)
void transpose_kernel(const float* __restrict__ w1, const float* __restrict__ w2,
                      float* __restrict__ w1t, float* __restrict__ w2t){
  int i = blockIdx.x*256 + threadIdx.x;
  if (i < 128*512){ int rr = i >> 9, k = i & 511; w1t[k*128 + rr] = w1[i]; }
  if (i < 64*128){ int rr = i >> 7, k = i & 127; w2t[k*64 + rr] = w2[i]; }
}

__global__ __launch_bounds__(128)
void mlp1_kernel(const float* __restrict__ hs1, const float* __restrict__ w1t,
                 const float* __restrict__ b1, float* __restrict__ z1){
  __shared__ float hsl[2048];             // 4 rows x 512
  const int tid = threadIdx.x;
  const size_t row0 = (size_t)blockIdx.x*4;
  #pragma unroll
  for (int q=0;q<4;q++){
    int idx = tid + q*128;
    *(float4*)&hsl[idx*4] = *(const float4*)&hs1[row0*512 + idx*4];
  }
  __syncthreads();
  float a0=0.f,a1=0.f,a2=0.f,a3=0.f;
  #pragma unroll 4
  for (int k=0;k<512;k++){
    float wv = w1t[k*128 + tid];
    a0 = fmaf(wv, hsl[k],      a0);
    a1 = fmaf(wv, hsl[512+k],  a1);
    a2 = fmaf(wv, hsl[1024+k], a2);
    a3 = fmaf(wv, hsl[1536+k], a3);
  }
  float bb = b1[tid];
  z1[(row0+0)*128 + tid] = fmaxf(a0+bb, 0.f);
  z1[(row0+1)*128 + tid] = fmaxf(a1+bb, 0.f);
  z1[(row0+2)*128 + tid] = fmaxf(a2+bb, 0.f);
  z1[(row0+3)*128 + tid] = fmaxf(a3+bb, 0.f);
}

template<int NF_>
__global__ void stats_partial(const float* __restrict__ z, float* __restrict__ part){
  const int cf = threadIdx.x;
  const int b  = blockIdx.x;             // 64 blocks x 512 rows
  float s=0.f, sq=0.f;
  const float* p = z + (size_t)b*512*NF_ + cf;
  for (int rr=0; rr<512; rr++){
    float v = p[(size_t)rr*NF_];
    s += v; sq = fmaf(v, v, sq);
  }
  part[(b*NF_ + cf)*2+0] = s;
  part[(b*NF_ + cf)*2+1] = sq;
}

template<int NF_>
__global__ void stats_final(const float* __restrict__ part, const float* __restrict__ gamma,
                            const float* __restrict__ beta, float* __restrict__ sc,
                            float* __restrict__ sh){
  const int cf = threadIdx.x;
  float s=0.f, sq=0.f;
  for (int b=0;b<64;b++){ s += part[(b*NF_+cf)*2]; sq += part[(b*NF_+cf)*2+1]; }
  const float inv = 1.f/32768.f;
  float m = s*inv;
  float v = fmaf(sq, inv, -m*m);
  float scale = gamma[cf]*rsqrtf(v + 1e-5f);
  sc[cf] = scale;
  sh[cf] = fmaf(-m, scale, beta[cf]);
}

__global__ __launch_bounds__(64)
void mlp2_kernel(const float* __restrict__ z1, const float* __restrict__ w2t,
                 const float* __restrict__ b2, const float* __restrict__ sc1,
                 const float* __restrict__ sh1, float* __restrict__ z2){
  __shared__ float zl[1024];              // 8 rows x 128 (BN-applied)
  const int tid = threadIdx.x;
  const size_t row0 = (size_t)blockIdx.x*8;
  #pragma unroll
  for (int q=0;q<4;q++){
    int idx = tid + q*64;                 // float4 index 0..255
    float4 v = *(const float4*)&z1[row0*128 + idx*4];
    int k0 = (idx*4) & 127;
    v.x = fmaf(v.x, sc1[k0+0], sh1[k0+0]);
    v.y = fmaf(v.y, sc1[k0+1], sh1[k0+1]);
    v.z = fmaf(v.z, sc1[k0+2], sh1[k0+2]);
    v.w = fmaf(v.w, sc1[k0+3], sh1[k0+3]);
    *(float4*)&zl[idx*4] = v;
  }
  __syncthreads();
  float acc[8] = {0.f,0.f,0.f,0.f,0.f,0.f,0.f,0.f};
  #pragma unroll 4
  for (int k=0;k<128;k++){
    float wv = w2t[k*64 + tid];
    #pragma unroll
    for (int rr=0;rr<8;rr++) acc[rr] = fmaf(wv, zl[rr*128 + k], acc[rr]);
  }
  float bb = b2[tid];
  #pragma unroll
  for (int rr=0;rr<8;rr++)
    z2[(row0+rr)*64 + tid] = fmaxf(acc[rr]+bb, 0.f);
}

__global__ __launch_bounds__(256)
void mlp3_kernel(const float* __restrict__ z2, const float* __restrict__ w3,
                 const float* __restrict__ b3, const float* __restrict__ sc2,
                 const float* __restrict__ sh2, float* __restrict__ out){
  const int tid = threadIdx.x;
  const int lane = tid & 63;
  const size_t row = (size_t)blockIdx.x*4 + (tid>>6);   // one wave per row
  float v = fmaf(z2[row*64 + lane], sc2[lane], sh2[lane]);
  float p0 = v*w3[lane], p1 = v*w3[64+lane], p2 = v*w3[128+lane];
  #pragma unroll
  for (int off=32; off; off>>=1){
    p0 += __shfl_xor(p0, off);
    p1 += __shfl_xor(p1, off);
    p2 += __shfl_xor(p2, off);
  }
  if (lane == 0){
    out[row*3+0] = p0 + b3[0];
    out[row*3+1] = p1 + b3[1];
    out[row*3+2] = p2 + b3[2];
  }
}

extern "C" void kernel_launch(void* const* d_in, const int* in_sizes, int n_in,
                              void* d_out, int out_size, void* d_ws, size_t ws_size,
                              hipStream_t stream){
  (void)in_sizes; (void)n_in; (void)out_size;
  const float* x    = (const float*)d_in[0];
  const float* wih0 = (const float*)d_in[1];
  const float* whh0 = (const float*)d_in[2];
  const float* bih0 = (const float*)d_in[3];
  const float* bhh0 = (const float*)d_in[4];
  const float* wih1 = (const float*)d_in[5];
  const float* whh1 = (const float*)d_in[6];
  const float* bih1 = (const float*)d_in[7];
  const float* bhh1 = (const float*)d_in[8];
  const float* w1   = (const float*)d_in[9];
  const float* b1   = (const float*)d_in[10];
  const float* g1   = (const float*)d_in[11];
  const float* be1  = (const float*)d_in[12];
  const float* w2   = (const float*)d_in[13];
  const float* b2   = (const float*)d_in[14];
  const float* g2   = (const float*)d_in[15];
  const float* be2  = (const float*)d_in[16];
  const float* w3   = (const float*)d_in[17];
  const float* b3   = (const float*)d_in[18];
  float* ws  = (float*)d_ws;
  float* out = (float*)d_out;

  if (ws_size < (size_t)134217728ull) return;   // proven available in round 1

  // comm buffers (disjoint, fp32): [0,64MB) hs0, [64,128MB) hs1
  float* hs0 = ws;                    // [32768][512]
  float* hs1 = ws + 16777216;         // [32768][512]
  // head scratch aliases hs0 region; ALL of it written only AFTER the scan
  float* z1    = ws;                  // [32768][128] = 16 MB
  float* z2    = ws + 4194304;        // [32768][64]  =  8 MB
  float* w1t   = ws + 6291456;        // [512][128]
  float* w2t   = w1t + 65536;         // [128][64]
  float* part1 = w2t + 8192;          // [64][128][2]
  float* part2 = part1 + 16384;       // [64][64][2]
  float* sc1   = part2 + 8192;
  float* sh1   = sc1 + 128;
  float* sc2   = sh1 + 128;
  float* sh2   = sc2 + 64;

  poison_kernel<<<1024, 256, 0, stream>>>((uint64_t*)ws, 16777216);
  lstm_persistent<<<2*NWGL, WGT, 0, stream>>>(x, wih0, whh0, bih0, bhh0,
                                              wih1, whh1, bih1, bhh1, hs0, hs1);
  transpose_kernel<<<256, 256, 0, stream>>>(w1, w2, w1t, w2t);
  mlp1_kernel<<<8192, 128, 0, stream>>>(hs1, w1t, b1, z1);
  stats_partial<128><<<64, 128, 0, stream>>>(z1, part1);
  stats_final<128><<<1, 128, 0, stream>>>(part1, g1, be1, sc1, sh1);
  mlp2_kernel<<<4096, 64, 0, stream>>>(z1, w2t, b2, sc1, sh1, z2);
  stats_partial<64><<<64, 64, 0, stream>>>(z2, part2);
  stats_final<64><<<1, 64, 0, stream>>>(part2, g2, be2, sc2, sh2);
  mlp3_kernel<<<8192, 256, 0, stream>>>(z2, w3, b3, sc2, sh2, out);
}